// Round 17
// baseline (74.710 us; speedup 1.0000x reference)
//
#include <hip/hip_runtime.h>
#include <stdint.h>

typedef _Float16 half_t;
typedef _Float16 v8h __attribute__((ext_vector_type(8)));
typedef float v4f __attribute__((ext_vector_type(4)));

#define HH 256
#define WW 256
#define HW (HH*WW)
#define TH 16
#define TW 16
#define NTHREADS 512
#define L2E 1.44269504088896340736f

// No LDS, no barrier: fr fragments load straight from global (L1/L2-served),
// converted inline. 8 waves/block, wave w owns query rows y0+2w, y0+2w+1.
__global__ __launch_bounds__(NTHREADS, 4)
void corr_recon(const float* __restrict__ ft, const float* __restrict__ fr,
                const float* __restrict__ img, float* __restrict__ out)
{
    // XCD-chunked bijective swizzle: 512 blocks = 8 chunks of 64
    const int bid0 = blockIdx.x;
    const int bid  = (bid0 & 7) * 64 + (bid0 >> 3);

    const int b0  = bid >> 8;
    const int rb  = bid & 255;
    const int y0  = (rb >> 4) * TH;    // 16 row-bands of 16
    const int x0t = (rb & 15) * TW;    // 16 col-bands of 16

    const int tid  = threadIdx.x;
    const int lane = tid & 63;
    const int w    = tid >> 6;         // wave 0..7 -> query rows y0+2w, y0+2w+1
    const int n    = lane & 15;        // MFMA col lane (key px slot)
    const int g    = lane >> 4;        // MFMA k-group

    const float* frb = fr  + (size_t)b0 * 32 * HW;
    const float* ftb = ft  + (size_t)b0 * 32 * HW;
    const float* imb = img + (size_t)b0 * HW;

    // per-lane key-px x coordinates (clamped) + validity
    const int gx0  = x0t - 6 + n;      // [-6, 249] -> only lower bound can fail
    const int gx1  = gx0 + 16;         // [10, 265] -> only upper bound can fail
    const int gx0c = max(gx0, 0);
    const int gx1c = min(gx1, WW-1);
    const bool okx0 = (gx0 >= 0);
    const bool okx1 = (gx1 < WW);

    // ---- img -> registers (28 scalars/lane; same as R16) ----
    float iw0r[14], iw1r[14];
    #pragma unroll
    for (int u = 0; u < 14; ++u) {
        const int gy  = y0 + 2*w - 6 + u;
        const int gyc = min(max(gy, 0), HH-1);
        const bool oky = (gy == gyc);
        const float v0 = imb[(size_t)gyc * WW + gx0c];
        const float v1 = imb[(size_t)gyc * WW + gx1c];
        iw0r[u] = (oky && okx0) ? v0 : 0.f;
        iw1r[u] = (oky && okx1) ? v1 : 0.f;
    }

    // ---- A fragments: 2 query rows, ch {4g+j, 16+4g+j}, pre-scaled by log2e ----
    const int y = y0 + 2*w;
    v8h a0, a1;
    {
        const float* fa = ftb + (size_t)y * WW + (x0t + n);
        #pragma unroll
        for (int j = 0; j < 4; ++j) {
            a0[j]   = (half_t)(fa[(size_t)(4*g + j)      * HW] * L2E);
            a0[4+j] = (half_t)(fa[(size_t)(16 + 4*g + j) * HW] * L2E);
            a1[j]   = (half_t)(fa[WW + (size_t)(4*g + j)      * HW] * L2E);
            a1[4+j] = (half_t)(fa[WW + (size_t)(16 + 4*g + j) * HW] * L2E);
        }
    }

    // ---- per-lane displacement-band biases (log2 domain; exp2(-1e4)==0) ----
    v4f bias0, bias1;
    #pragma unroll
    for (int r = 0; r < 4; ++r) {
        const int m  = 4*g + r;
        const int d0 = n - m;            // key-tile 0
        const int d1 = 16 + n - m;       // key-tile +16
        bias0[r] = (d0 >= 0 && d0 <= 12) ? 0.f : -1e4f;
        bias1[r] = (d1 >= 0 && d1 <= 12) ? 0.f : -1e4f;
    }
    const int dm = n - 4*g;              // select: cond_r = (dm >= r)

    v4f lp0 = {0,0,0,0}, ap0 = {0,0,0,0};
    v4f lp1 = {0,0,0,0}, ap1 = {0,0,0,0};

    auto STEP = [&](const v8h& a, v4f& lp, v4f& ap,
                    const v8h& B0, const v8h& B1, float iw0, float iw1) {
        v4f c0 = __builtin_amdgcn_mfma_f32_16x16x32_f16(a, B0, bias0, 0, 0, 0);
        v4f c1 = __builtin_amdgcn_mfma_f32_16x16x32_f16(a, B1, bias1, 0, 0, 0);
        #pragma unroll
        for (int r = 0; r < 4; ++r) {
            const bool cond = (dm >= r);
            float cs  = cond ? c0[r] : c1[r];
            float iws = cond ? iw0   : iw1;
            float e = __builtin_amdgcn_exp2f(cs);
            lp[r] += e;
            ap[r] += e * iws;
        }
    };

    // fragment channel base for this lane group: channels 4g.. via pb0
    const float* pb0 = frb + (size_t)(4*g) * HW;

    // ---- main loop, fully unrolled; B fragments straight from global ----
    #pragma unroll
    for (int u = 0; u < 14; ++u) {
        const int gy  = y0 + 2*w - 6 + u;
        const int gyc = min(max(gy, 0), HH-1);
        const bool oky = (gy == gyc);
        const float* r0 = pb0 + (size_t)gyc * WW;

        float f0[8], f1[8];
        #pragma unroll
        for (int j = 0; j < 4; ++j) {
            f0[j]   = r0[(size_t)j        * HW + gx0c];
            f0[4+j] = r0[(size_t)(16 + j) * HW + gx0c];
            f1[j]   = r0[(size_t)j        * HW + gx1c];
            f1[4+j] = r0[(size_t)(16 + j) * HW + gx1c];
        }
        const bool m0 = oky && okx0;
        const bool m1 = oky && okx1;
        v8h B0, B1;
        #pragma unroll
        for (int j = 0; j < 8; ++j) {
            B0[j] = (half_t)(m0 ? f0[j] : 0.f);
            B1[j] = (half_t)(m1 ? f1[j] : 0.f);
        }

        if (u <= 12) STEP(a0, lp0, ap0, B0, B1, iw0r[u], iw1r[u]);
        if (u >= 1)  STEP(a1, lp1, ap1, B0, B1, iw0r[u], iw1r[u]);
    }

    // ---- reduce over the 16 key-px lanes; write 2 rows × 16 px per wave ----
    #pragma unroll
    for (int r = 0; r < 4; ++r) {
        float l0 = lp0[r], v0 = ap0[r], l1 = lp1[r], v1 = ap1[r];
        l0 += __shfl_xor(l0, 1);  v0 += __shfl_xor(v0, 1);
        l1 += __shfl_xor(l1, 1);  v1 += __shfl_xor(v1, 1);
        l0 += __shfl_xor(l0, 2);  v0 += __shfl_xor(v0, 2);
        l1 += __shfl_xor(l1, 2);  v1 += __shfl_xor(v1, 2);
        l0 += __shfl_xor(l0, 4);  v0 += __shfl_xor(v0, 4);
        l1 += __shfl_xor(l1, 4);  v1 += __shfl_xor(v1, 4);
        l0 += __shfl_xor(l0, 8);  v0 += __shfl_xor(v0, 8);
        l1 += __shfl_xor(l1, 8);  v1 += __shfl_xor(v1, 8);
        lp0[r] = l0; ap0[r] = v0; lp1[r] = l1; ap1[r] = v1;
    }
    if (n < 4) {
        const float l0 = n==0 ? lp0[0] : n==1 ? lp0[1] : n==2 ? lp0[2] : lp0[3];
        const float v0 = n==0 ? ap0[0] : n==1 ? ap0[1] : n==2 ? ap0[2] : ap0[3];
        const float l1 = n==0 ? lp1[0] : n==1 ? lp1[1] : n==2 ? lp1[2] : lp1[3];
        const float v1 = n==0 ? ap1[0] : n==1 ? ap1[1] : n==2 ? ap1[2] : ap1[3];
        float* orow = out + (size_t)b0 * HW + (size_t)y * WW + x0t + 4*g + n;
        orow[0]  = v0 / l0;
        orow[WW] = v1 / l1;
    }
}

extern "C" void kernel_launch(void* const* d_in, const int* in_sizes, int n_in,
                              void* d_out, int out_size, void* d_ws, size_t ws_size,
                              hipStream_t stream)
{
    const float* ft  = (const float*)d_in[0];  // feats_t  (2,32,256,256) f32
    const float* fr  = (const float*)d_in[1];  // feats_r  (2,32,256,256) f32
    const float* img = (const float*)d_in[2];  // img_r    (2,1,256,256)  f32
    float* out = (float*)d_out;                // (2,1,256,256) f32
    (void)in_sizes; (void)n_in; (void)out_size; (void)d_ws; (void)ws_size;
    corr_recon<<<512, NTHREADS, 0, stream>>>(ft, fr, img, out);
}

// Round 18
// 30.651 us; speedup vs baseline: 2.4375x; 2.4375x over previous
//
#include <hip/hip_runtime.h>
#include <stdint.h>

typedef _Float16 half_t;
typedef _Float16 v8h __attribute__((ext_vector_type(8)));
typedef float v4f __attribute__((ext_vector_type(4)));

#define HH 256
#define WW 256
#define HW (HH*WW)
#define TH 16
#define TW 16
#define NTHREADS 512
#define L2E 1.44269504088896340736f

// No LDS, no barrier: fr fragments load straight from global (L1/L2-served).
// 8 waves/block, wave w owns query rows y0+2w, y0+2w+1.
// launch_bounds(512,2): VGPR cap 256 -> guaranteed spill-free (R17 failed at cap 64).
__global__ __launch_bounds__(NTHREADS, 2)
void corr_recon(const float* __restrict__ ft, const float* __restrict__ fr,
                const float* __restrict__ img, float* __restrict__ out)
{
    // XCD-chunked bijective swizzle: 512 blocks = 8 chunks of 64
    const int bid0 = blockIdx.x;
    const int bid  = (bid0 & 7) * 64 + (bid0 >> 3);

    const int b0  = bid >> 8;
    const int rb  = bid & 255;
    const int y0  = (rb >> 4) * TH;    // 16 row-bands of 16
    const int x0t = (rb & 15) * TW;    // 16 col-bands of 16

    const int tid  = threadIdx.x;
    const int lane = tid & 63;
    const int w    = tid >> 6;         // wave 0..7 -> query rows y0+2w, y0+2w+1
    const int n    = lane & 15;        // MFMA col lane (key px slot)
    const int g    = lane >> 4;        // MFMA k-group

    const float* frb = fr  + (size_t)b0 * 32 * HW;
    const float* ftb = ft  + (size_t)b0 * 32 * HW;
    const float* imb = img + (size_t)b0 * HW;

    // per-lane key-px x coordinates (clamped) + validity
    const int gx0  = x0t - 6 + n;      // [-6, 249] -> only lower bound can fail
    const int gx1  = gx0 + 16;         // [10, 265] -> only upper bound can fail
    const int gx0c = max(gx0, 0);
    const int gx1c = min(gx1, WW-1);
    const bool okx0 = (gx0 >= 0);
    const bool okx1 = (gx1 < WW);

    // ---- A fragments: 2 query rows, ch {4g+j, 16+4g+j}, pre-scaled by log2e ----
    const int y = y0 + 2*w;
    v8h a0, a1;
    {
        const float* fa = ftb + (size_t)y * WW + (x0t + n);
        #pragma unroll
        for (int j = 0; j < 4; ++j) {
            a0[j]   = (half_t)(fa[(size_t)(4*g + j)      * HW] * L2E);
            a0[4+j] = (half_t)(fa[(size_t)(16 + 4*g + j) * HW] * L2E);
            a1[j]   = (half_t)(fa[WW + (size_t)(4*g + j)      * HW] * L2E);
            a1[4+j] = (half_t)(fa[WW + (size_t)(16 + 4*g + j) * HW] * L2E);
        }
    }

    // ---- per-lane displacement-band biases (log2 domain; exp2(-1e4)==0) ----
    v4f bias0, bias1;
    #pragma unroll
    for (int r = 0; r < 4; ++r) {
        const int m  = 4*g + r;
        const int d0 = n - m;            // key-tile 0
        const int d1 = 16 + n - m;       // key-tile +16
        bias0[r] = (d0 >= 0 && d0 <= 12) ? 0.f : -1e4f;
        bias1[r] = (d1 >= 0 && d1 <= 12) ? 0.f : -1e4f;
    }
    const int dm = n - 4*g;              // select: cond_r = (dm >= r)

    v4f lp0 = {0,0,0,0}, ap0 = {0,0,0,0};
    v4f lp1 = {0,0,0,0}, ap1 = {0,0,0,0};

    auto STEP = [&](const v8h& a, v4f& lp, v4f& ap,
                    const v8h& B0, const v8h& B1, float iw0, float iw1) {
        v4f c0 = __builtin_amdgcn_mfma_f32_16x16x32_f16(a, B0, bias0, 0, 0, 0);
        v4f c1 = __builtin_amdgcn_mfma_f32_16x16x32_f16(a, B1, bias1, 0, 0, 0);
        #pragma unroll
        for (int r = 0; r < 4; ++r) {
            const bool cond = (dm >= r);
            float cs  = cond ? c0[r] : c1[r];
            float iws = cond ? iw0   : iw1;
            float e = __builtin_amdgcn_exp2f(cs);
            lp[r] += e;
            ap[r] += e * iws;
        }
    };

    // fragment channel base for this lane group: channels 4g..
    const float* pb0 = frb + (size_t)(4*g) * HW;

    // ---- main loop, fully unrolled; B fragments + img straight from global ----
    #pragma unroll
    for (int u = 0; u < 14; ++u) {
        const int gy  = y0 + 2*w - 6 + u;
        const int gyc = min(max(gy, 0), HH-1);
        const bool oky = (gy == gyc);
        const float* r0 = pb0 + (size_t)gyc * WW;

        float f0[8], f1[8];
        #pragma unroll
        for (int j = 0; j < 4; ++j) {
            f0[j]   = r0[(size_t)j        * HW + gx0c];
            f0[4+j] = r0[(size_t)(16 + j) * HW + gx0c];
            f1[j]   = r0[(size_t)j        * HW + gx1c];
            f1[4+j] = r0[(size_t)(16 + j) * HW + gx1c];
        }
        const float* ir = imb + (size_t)gyc * WW;
        const float v0 = ir[gx0c];
        const float v1 = ir[gx1c];
        const float iw0 = (oky && okx0) ? v0 : 0.f;
        const float iw1 = (oky && okx1) ? v1 : 0.f;

        const bool m0 = oky && okx0;
        const bool m1 = oky && okx1;
        v8h B0, B1;
        #pragma unroll
        for (int j = 0; j < 8; ++j) {
            B0[j] = (half_t)(m0 ? f0[j] : 0.f);
            B1[j] = (half_t)(m1 ? f1[j] : 0.f);
        }

        if (u <= 12) STEP(a0, lp0, ap0, B0, B1, iw0, iw1);
        if (u >= 1)  STEP(a1, lp1, ap1, B0, B1, iw0, iw1);
    }

    // ---- reduce over the 16 key-px lanes; write 2 rows × 16 px per wave ----
    #pragma unroll
    for (int r = 0; r < 4; ++r) {
        float l0 = lp0[r], v0 = ap0[r], l1 = lp1[r], v1 = ap1[r];
        l0 += __shfl_xor(l0, 1);  v0 += __shfl_xor(v0, 1);
        l1 += __shfl_xor(l1, 1);  v1 += __shfl_xor(v1, 1);
        l0 += __shfl_xor(l0, 2);  v0 += __shfl_xor(v0, 2);
        l1 += __shfl_xor(l1, 2);  v1 += __shfl_xor(v1, 2);
        l0 += __shfl_xor(l0, 4);  v0 += __shfl_xor(v0, 4);
        l1 += __shfl_xor(l1, 4);  v1 += __shfl_xor(v1, 4);
        l0 += __shfl_xor(l0, 8);  v0 += __shfl_xor(v0, 8);
        l1 += __shfl_xor(l1, 8);  v1 += __shfl_xor(v1, 8);
        lp0[r] = l0; ap0[r] = v0; lp1[r] = l1; ap1[r] = v1;
    }
    if (n < 4) {
        const float l0 = n==0 ? lp0[0] : n==1 ? lp0[1] : n==2 ? lp0[2] : lp0[3];
        const float v0 = n==0 ? ap0[0] : n==1 ? ap0[1] : n==2 ? ap0[2] : ap0[3];
        const float l1 = n==0 ? lp1[0] : n==1 ? lp1[1] : n==2 ? lp1[2] : lp1[3];
        const float v1 = n==0 ? ap1[0] : n==1 ? ap1[1] : n==2 ? ap1[2] : ap1[3];
        float* orow = out + (size_t)b0 * HW + (size_t)y * WW + x0t + 4*g + n;
        orow[0]  = v0 / l0;
        orow[WW] = v1 / l1;
    }
}

extern "C" void kernel_launch(void* const* d_in, const int* in_sizes, int n_in,
                              void* d_out, int out_size, void* d_ws, size_t ws_size,
                              hipStream_t stream)
{
    const float* ft  = (const float*)d_in[0];  // feats_t  (2,32,256,256) f32
    const float* fr  = (const float*)d_in[1];  // feats_r  (2,32,256,256) f32
    const float* img = (const float*)d_in[2];  // img_r    (2,1,256,256)  f32
    float* out = (float*)d_out;                // (2,1,256,256) f32
    (void)in_sizes; (void)n_in; (void)out_size; (void)d_ws; (void)ws_size;
    corr_recon<<<512, NTHREADS, 0, stream>>>(ft, fr, img, out);
}